// Round 25
// baseline (246.051 us; speedup 1.0000x reference)
//
#include <hip/hip_runtime.h>
#include <hip/hip_bf16.h>

#define BB 2
#define SS 2048
#define EE 1024
#define HH 16
#define DD 64
#define MT (BB*SS)     // 4096 tokens
#define NQ (3*EE)      // 3072

typedef unsigned short u16;
typedef __bf16 bf16t;
typedef bf16t bf16x8 __attribute__((ext_vector_type(8)));
typedef short short8v __attribute__((ext_vector_type(8)));
typedef float f32x4 __attribute__((ext_vector_type(4)));

#define AS1 __attribute__((address_space(1)))
#define AS3 __attribute__((address_space(3)))

__device__ __forceinline__ u16 f2b(float f) {
  unsigned u = __builtin_bit_cast(unsigned, f);
  u += 0x7FFF + ((u >> 16) & 1);   // RNE
  return (u16)(u >> 16);
}

__device__ __forceinline__ unsigned cvtpk(float lo, float hi) {
  unsigned r;
  asm("v_cvt_pk_bf16_f32 %0, %1, %2" : "=v"(r) : "v"(lo), "v"(hi));
  return r;
}

__device__ __forceinline__ void gload_lds16(const void* g, void* l) {
  __builtin_amdgcn_global_load_lds((const AS1 void*)(g), (AS3 void*)(l), 16, 0, 0);
}

__device__ __forceinline__ f32x4 mfma_bf16(short8v a, short8v b, f32x4 c) {
  return __builtin_amdgcn_mfma_f32_16x16x32_bf16(
      __builtin_bit_cast(bf16x8, a), __builtin_bit_cast(bf16x8, b), c, 0, 0, 0);
}

// scale folded into Q: 1/sqrt(64) * log2(e)
#define QSCALE 0.18033688f

// ---------------- prologue: cast x -> bf16 ----------------
__global__ void __launch_bounds__(256) cast_kernel(const float* __restrict__ in,
                                                   u16* __restrict__ out, int n) {
  int i = (blockIdx.x * 256 + threadIdx.x) * 4;
  if (i + 3 < n) {
    float4 v = *(const float4*)(in + i);
    ushort4 o;
    o.x = f2b(v.x); o.y = f2b(v.y); o.z = f2b(v.z); o.w = f2b(v.w);
    *(ushort4*)(out + i) = o;
  }
}

// Both W transposes in ONE launch. W [K][N] f32 -> WT [N][K] bf16, 64x64 tiles.
__global__ void __launch_bounds__(256) transpose2_kernel(
    const float* __restrict__ Wq, u16* __restrict__ WqT,
    const float* __restrict__ Wo, u16* __restrict__ WoT) {
  __shared__ float t[64][65];
  int bid = blockIdx.x;
  const float* W; u16* WT; int N, xt, yt;
  if (bid < 768) { W = Wq; WT = WqT; N = NQ; xt = bid % 48; yt = bid / 48; }
  else { int b2 = bid - 768; W = Wo; WT = WoT; N = EE; xt = b2 & 15; yt = b2 >> 4; }
  const int K = EE;
  int k0 = yt * 64, n0 = xt * 64;
  int r = threadIdx.x >> 4;          // 0..15
  int c4 = (threadIdx.x & 15) * 4;   // 0..60
#pragma unroll
  for (int i = 0; i < 4; ++i) {
    float4 v = *(const float4*)(W + (size_t)(k0 + r + i * 16) * N + n0 + c4);
    t[r + i * 16][c4 + 0] = v.x; t[r + i * 16][c4 + 1] = v.y;
    t[r + i * 16][c4 + 2] = v.z; t[r + i * 16][c4 + 3] = v.w;
  }
  __syncthreads();
#pragma unroll
  for (int i = 0; i < 4; ++i) {
    ushort4 o;
    o.x = f2b(t[c4 + 0][r + i * 16]); o.y = f2b(t[c4 + 1][r + i * 16]);
    o.z = f2b(t[c4 + 2][r + i * 16]); o.w = f2b(t[c4 + 3][r + i * 16]);
    *(ushort4*)(WT + (size_t)(n0 + r + i * 16) * K + k0 + c4) = o;
  }
}

// ---------------- QKV GEMM (2-phase dbuf + XCD swizzle, round-21) -----------
__global__ void __launch_bounds__(256) gemm_qkv_kernel(
    const u16* __restrict__ A, const u16* __restrict__ BT,
    const float* __restrict__ bias,
    u16* __restrict__ Qs, u16* __restrict__ Ks, u16* __restrict__ Vt) {
  __shared__ u16 As[8192];   // 2 x 128x32
  __shared__ u16 Bs[8192];
  const int K = EE;
  int tid = threadIdx.x;
  int w = tid >> 6, lane = tid & 63;
  int g = lane >> 4, q = lane & 15;
  int bid = blockIdx.x;
  int xcd = bid & 7, idx = bid >> 3;           // idx 0..95
  int xt = xcd * 3 + (idx % 3);                // 0..23
  int yt = idx / 3;                            // 0..31
  int m0 = yt * 128, n0 = xt * 128;
  int wm = (w >> 1) * 64, wn = (w & 1) * 64;

  f32x4 acc[4][4] = {};

  int r = tid >> 2;
  int kc = (tid & 3) * 8;
  const u16* ga = A + (size_t)(m0 + r) * K + kc;
  const u16* gb = BT + (size_t)(n0 + r) * K + kc;
  u16* lA0 = As + w * 512;
  u16* lA1 = As + 2048 + w * 512;
  u16* lB0 = Bs + w * 512;
  u16* lB1 = Bs + 2048 + w * 512;

  gload_lds16(ga, lA0);
  gload_lds16(ga + 64 * K, lA1);
  gload_lds16(gb, lB0);
  gload_lds16(gb + 64 * K, lB1);
  ga += 32; gb += 32;
  __syncthreads();

  int cur = 0;
  for (int k0 = 0; k0 < K; k0 += 32) {
    if (k0 + 32 < K) {               // issue next-tile staging BEFORE compute
      int nx = (cur ^ 1) * 4096;
      gload_lds16(ga, lA0 + nx);
      gload_lds16(ga + 64 * K, lA1 + nx);
      gload_lds16(gb, lB0 + nx);
      gload_lds16(gb + 64 * K, lB1 + nx);
      ga += 32; gb += 32;
    }
    const u16* Ab = As + cur * 4096;
    const u16* Bb = Bs + cur * 4096;
    short8v af[4], bfv[4];
#pragma unroll
    for (int m = 0; m < 4; ++m)
      af[m] = *(const short8v*)(Ab + (wm + m * 16 + q) * 32 + g * 8);
#pragma unroll
    for (int n = 0; n < 4; ++n)
      bfv[n] = *(const short8v*)(Bb + (wn + n * 16 + q) * 32 + g * 8);
#pragma unroll
    for (int m = 0; m < 4; ++m)
#pragma unroll
      for (int n = 0; n < 4; ++n)
        acc[m][n] = mfma_bf16(af[m], bfv[n], acc[m][n]);
    __syncthreads();                 // drains staged loads; swap safe
    cur ^= 1;
  }

#pragma unroll
  for (int m = 0; m < 4; ++m) {
    int row0 = m0 + wm + m * 16 + g * 4;
#pragma unroll
    for (int n = 0; n < 4; ++n) {
      int col = n0 + wn + n * 16 + q;
      float bi = bias[col];
      int t = col >> 10;
      int h = (col >> 6) & 15;
      int d = col & 63;
      int b = row0 >> 11, s0 = row0 & 2047;
      size_t bh = (size_t)b * HH + h;
      if (t == 2) {
        ushort4 vv;
        vv.x = f2b(acc[m][n][0] + bi); vv.y = f2b(acc[m][n][1] + bi);
        vv.z = f2b(acc[m][n][2] + bi); vv.w = f2b(acc[m][n][3] + bi);
        *(ushort4*)&Vt[(bh * DD + d) * SS + s0] = vv;
      } else if (t == 0) {
#pragma unroll
        for (int r2 = 0; r2 < 4; ++r2)
          Qs[(bh * SS + s0 + r2) * DD + d] = f2b((acc[m][n][r2] + bi) * QSCALE);
      } else {
#pragma unroll
        for (int r2 = 0; r2 < 4; ++r2)
          Ks[(bh * SS + s0 + r2) * DD + d] = f2b(acc[m][n][r2] + bi);
      }
    }
  }
}

// ---------------- causal flash attention (256-row block, 32 rows/wave) ------
// Round-18 structure (proven CORRECT; failed only on compiler VGPR choice):
// 1024 threads = 16 waves over a 256-row chunk; halves hv=0/1 (8 waves x 32
// q-rows) split the KV range; chunks paired (c, 7-c) -> 256 blocks x exactly
// 18 phases, uniform, 1 block/CU. __launch_bounds__(1024, 4) = 4 waves/EU ->
// 128-VGPR cap so the m=2 body (~112 regs, round-16 measured) does NOT spill
// (round-18's default cap was 64 -> scratch catastrophe). K/V dbuf via
// global_load_lds (rule-21 swizzle), round-12 sync. P 2KB/wave reused across
// m. Halves merged via LDS partials reusing the K/V region.
__global__ void __launch_bounds__(1024, 4) attn_kernel(
    const u16* __restrict__ Qg, const u16* __restrict__ Kg,
    const u16* __restrict__ Vg, u16* __restrict__ O) {
  // K: hv*16K + buf*8K @0 (32K) | V same @32768 | P 16x2K @65536 | ml @98304
  __shared__ char lds[100352];
  const int tid = threadIdx.x;
  const int w = tid >> 6, lane = tid & 63;
  const int hv = w >> 3, ws = w & 7;
  const int g = lane >> 4, q = lane & 15;
  const int bid = blockIdx.x;          // 0..255
  const int bh = bid & 31;             // bid%8 -> XCD; K/V L2-resident
  const int c0 = bid >> 5;             // 0..7
  const int b = bh >> 4, h = bh & 15;
  char* Pw = lds + 65536 + w * 2048;
  const int qsw = (q & 7) << 4;

  const char* Qp = (const char*)Qg + (size_t)bh * (SS * 128);
  const char* Kp = (const char*)Kg + (size_t)bh * (SS * 128);
  const char* Vp = (const char*)Vg + (size_t)bh * (SS * 128);  // [d][s]

  // per-half staging map (512 threads/half, one 16B chunk each per matrix)
  const int tl = tid & 511;
  const int srow = tl >> 3;
  const int ssw = ((tl & 7) * 16) ^ ((srow & 7) << 4);
  const char* Ksrc = Kp + srow * 128 + ssw;               // + tile*8192
  const char* Vsrc = Vp + (size_t)srow * (SS * 2) + ssw;  // + tile*128
  char* Kdst = lds + hv * 16384 + ws * 1024;              // + buf*8192
  char* Vdst = lds + 32768 + hv * 16384 + ws * 1024;

#pragma unroll 1
  for (int pass = 0; pass < 2; ++pass) {
    const int c = pass ? (7 - c0) : c0;
    const int hl = 2 * (c + 1);        // tiles per half
    const int t0 = hv * hl;            // this half's first global tile
    const int qw = c * 256 + ws * 32;  // wave's first q row

    short8v aq[2][2];
#pragma unroll
    for (int m = 0; m < 2; ++m)
#pragma unroll
      for (int j = 0; j < 2; ++j)
        aq[m][j] = *(const short8v*)(Qp + (size_t)(qw + m * 16 + q) * 128 + j * 64 + g * 16);

    f32x4 oacc[2][4] = {};
    float mrun[2], lrun[2];
#pragma unroll
    for (int m = 0; m < 2; ++m) { mrun[m] = -1e30f; lrun[m] = 0.f; }

    // prologue: stage this half's tile t0 into buf0
    gload_lds16(Ksrc + (size_t)t0 * 8192, Kdst);
    gload_lds16(Vsrc + t0 * 128, Vdst);
    __syncthreads();

    for (int s = 0; s < hl; ++s) {
      const int buf = s & 1;
      if (s + 1 < hl) {                // issue next-tile staging before compute
        gload_lds16(Ksrc + (size_t)(t0 + s + 1) * 8192, Kdst + (buf ^ 1) * 8192);
        gload_lds16(Vsrc + (t0 + s + 1) * 128, Vdst + (buf ^ 1) * 8192);
      }
      const int kv0 = (t0 + s) << 6;
      if (kv0 <= qw + 31) {            // wave has unmasked work this tile
        const char* Kc = lds + hv * 16384 + buf * 8192;
        const char* Vc = lds + 32768 + hv * 16384 + buf * 8192;
        // ---- K fragments (shared across both m) ----
        short8v kf[4][2];
#pragma unroll
        for (int cc = 0; cc < 4; ++cc) {
          const char* kb = Kc + (cc * 16 + q) * 128;
          kf[cc][0] = *(const short8v*)(kb + ((g * 16) ^ qsw));
          kf[cc][1] = *(const short8v*)(kb + ((64 + g * 16) ^ qsw));
        }
        // ---- S^T = K Q^T for both 16-row frags ----
        f32x4 st[2][4];
        __builtin_amdgcn_s_setprio(1);
#pragma unroll
        for (int m = 0; m < 2; ++m)
#pragma unroll
          for (int cc = 0; cc < 4; ++cc) {
            f32x4 z = {};
            z = mfma_bf16(kf[cc][0], aq[m][0], z);
            z = mfma_bf16(kf[cc][1], aq[m][1], z);
            st[m][cc] = z;
          }
        __builtin_amdgcn_s_setprio(0);
        // ---- V^T fragments (shared across both m) ----
        short8v vf[4][2];
#pragma unroll
        for (int v = 0; v < 4; ++v) {
          const char* vb = Vc + (v * 16 + q) * 128;
          vf[v][0] = *(const short8v*)(vb + ((g * 16) ^ qsw));
          vf[v][1] = *(const short8v*)(vb + ((64 + g * 16) ^ qsw));
        }
        // ---- causal mask (diagonal tiles only) ----
        if (kv0 + 63 > qw) {
#pragma unroll
          for (int m = 0; m < 2; ++m) {
            int row = qw + m * 16 + q;
#pragma unroll
            for (int cc = 0; cc < 4; ++cc) {
              int kvb = kv0 + cc * 16 + g * 4;
#pragma unroll
              for (int r2 = 0; r2 < 4; ++r2)
                if (kvb + r2 > row) st[m][cc][r2] = -1e30f;
            }
          }
        }
        // ---- per-m online softmax + P pack + PV (P buffer reused) ----
#pragma unroll
        for (int m = 0; m < 2; ++m) {
          f32x4 t01, t23;
#pragma unroll
          for (int r2 = 0; r2 < 4; ++r2) {
            t01[r2] = fmaxf(st[m][0][r2], st[m][1][r2]);
            t23[r2] = fmaxf(st[m][2][r2], st[m][3][r2]);
          }
          float mx = fmaxf(fmaxf(fmaxf(t01[0], t01[1]), fmaxf(t01[2], t01[3])),
                           fmaxf(fmaxf(t23[0], t23[1]), fmaxf(t23[2], t23[3])));
          mx = fmaxf(mx, __shfl_xor(mx, 16));
          mx = fmaxf(mx, __shfl_xor(mx, 32));
          if (!__all(mx - mrun[m] <= 8.f)) {  // T13 defer-max
            float mnew = fmaxf(mrun[m], mx);
            float alpha = exp2f(mrun[m] - mnew);
            mrun[m] = mnew;
            lrun[m] *= alpha;
#pragma unroll
            for (int vfi = 0; vfi < 4; ++vfi)
#pragma unroll
              for (int r2 = 0; r2 < 4; ++r2) oacc[m][vfi][r2] *= alpha;
          }
          f32x4 sum4 = {};
#pragma unroll
          for (int cc = 0; cc < 4; ++cc)
#pragma unroll
            for (int r2 = 0; r2 < 4; ++r2) {
              float pv = exp2f(st[m][cc][r2] - mrun[m]);
              st[m][cc][r2] = pv;
              sum4[r2] += pv;
            }
          float sm = (sum4[0] + sum4[1]) + (sum4[2] + sum4[3]);
          sm += __shfl_xor(sm, 16);
          sm += __shfl_xor(sm, 32);
          lrun[m] += sm;
          char* basep = Pw + q * 128;
#pragma unroll
          for (int cc = 0; cc < 4; ++cc) {
            unsigned p01 = cvtpk(st[m][cc][0], st[m][cc][1]);
            unsigned p23 = cvtpk(st[m][cc][2], st[m][cc][3]);
            *(unsigned*)(basep + ((32 * cc + 8 * g + 0) ^ qsw)) = p01;
            *(unsigned*)(basep + ((32 * cc + 8 * g + 4) ^ qsw)) = p23;
          }
          short8v pa0 = *(const short8v*)(basep + ((g * 16) ^ qsw));
          short8v pa1 = *(const short8v*)(basep + ((64 + g * 16) ^ qsw));
          __builtin_amdgcn_s_setprio(1);
#pragma unroll
          for (int vfi = 0; vfi < 4; ++vfi) {
            oacc[m][vfi] = mfma_bf16(vf[vfi][0], pa0, oacc[m][vfi]);
            oacc[m][vfi] = mfma_bf16(vf[vfi][1], pa1, oacc[m][vfi]);
          }
          __builtin_amdgcn_s_setprio(0);
        }
      }
      __syncthreads();                 // staged loads drained; buffers safe
    }

    // ---- merge halves: hv=1 publishes partials (reuse K/V LDS), hv=0 merges
    if (hv) {
      char* ob = lds + ws * 8192;
#pragma unroll
      for (int m = 0; m < 2; ++m) {
#pragma unroll
        for (int vfi = 0; vfi < 4; ++vfi)
          *(f32x4*)(ob + (m * 4 + vfi) * 1024 + lane * 16) = oacc[m][vfi];
        if (g == 0)
          *(float2*)(lds + 98304 + (ws * 32 + m * 16 + q) * 8) =
              make_float2(mrun[m], lrun[m]);
      }
    }
    __syncthreads();
    if (!hv) {
      const char* ob = lds + ws * 8192;
#pragma unroll
      for (int m = 0; m < 2; ++m) {
        float2 ml = *(const float2*)(lds + 98304 + (ws * 32 + m * 16 + q) * 8);
        float mf = fmaxf(mrun[m], ml.x);
        float a0 = exp2f(mrun[m] - mf);
        float a1 = exp2f(ml.x - mf);
        float inv = 1.0f / (a0 * lrun[m] + a1 * ml.y);
        a0 *= inv; a1 *= inv;
        int row = qw + m * 16 + q;
        char* obase = (char*)O + (((size_t)b * SS + row) * EE + h * 64) * 2;
#pragma unroll
        for (int vfi = 0; vfi < 4; ++vfi) {
          f32x4 o1 = *(const f32x4*)(ob + (m * 4 + vfi) * 1024 + lane * 16);
          uint2 o;
          o.x = cvtpk(a0 * oacc[m][vfi][0] + a1 * o1[0],
                      a0 * oacc[m][vfi][1] + a1 * o1[1]);
          o.y = cvtpk(a0 * oacc[m][vfi][2] + a1 * o1[2],
                      a0 * oacc[m][vfi][3] + a1 * o1[3]);
          *(uint2*)(obase + (vfi * 16 + g * 4) * 2) = o;
        }
      }
    }
    __syncthreads();                   // K/V region free for next pass
  }
}

// ---------------- output projection GEMM (2-phase dbuf + XCD swizzle) -------
__global__ void __launch_bounds__(256) gemm_out_kernel(
    const u16* __restrict__ A, const u16* __restrict__ BT,
    const float* __restrict__ bias, float* __restrict__ Cout) {
  __shared__ u16 As[8192];
  __shared__ u16 Bs[8192];
  const int K = EE;
  int tid = threadIdx.x;
  int w = tid >> 6, lane = tid & 63;
  int g = lane >> 4, q = lane & 15;
  int bid = blockIdx.x;
  int xt = bid & 7, yt = bid >> 3;     // xcd-owned N column
  int m0 = yt * 128, n0 = xt * 128;
  int wm = (w >> 1) * 64, wn = (w & 1) * 64;

  f32x4 acc[4][4] = {};

  int r = tid >> 2;
  int kc = (tid & 3) * 8;
  const u16* ga = A + (size_t)(m0 + r) * K + kc;
  const u16* gb = BT + (size_t)(n0 + r) * K + kc;
  u16* lA0 = As + w * 512;
  u16* lA1 = As + 2048 + w * 512;
  u16* lB0 = Bs + w * 512;
  u16* lB1 = Bs + 2048 + w * 512;

  gload_lds16(ga, lA0);
  gload_lds16(ga + 64 * K, lA1);
  gload_lds16(gb, lB0);
  gload_lds16(gb + 64 * K, lB1);
  ga += 32; gb += 32;
  __syncthreads();

  int cur = 0;
  for (int k0 = 0; k0 < K; k0 += 32) {
    if (k0 + 32 < K) {
      int nx = (cur ^ 1) * 4096;
      gload_lds16(ga, lA0 + nx);
      gload_lds16(ga + 64 * K, lA1 + nx);
      gload_lds16(gb, lB0 + nx);
      gload_lds16(gb + 64 * K, lB1 + nx);
      ga += 32; gb += 32;
    }
    const u16* Ab = As + cur * 4096;
    const u16* Bb = Bs + cur * 4096;
    short8v af[4], bfv[4];
#pragma unroll
    for (int m = 0; m < 4; ++m)
      af[m] = *(const short8v*)(Ab + (wm + m * 16 + q) * 32 + g * 8);
#pragma unroll
    for (int n = 0; n < 4; ++n)
      bfv[n] = *(const short8v*)(Bb + (wn + n * 16 + q) * 32 + g * 8);
#pragma unroll
    for (int m = 0; m < 4; ++m)
#pragma unroll
      for (int n = 0; n < 4; ++n)
        acc[m][n] = mfma_bf16(af[m], bfv[n], acc[m][n]);
    __syncthreads();
    cur ^= 1;
  }

#pragma unroll
  for (int m = 0; m < 4; ++m) {
    int row0 = m0 + wm + m * 16 + g * 4;
#pragma unroll
    for (int n = 0; n < 4; ++n) {
      int col = n0 + wn + n * 16 + q;
      float bi = bias[col];
#pragma unroll
      for (int r2 = 0; r2 < 4; ++r2) {
        int row = row0 + r2;
        Cout[(size_t)row * EE + col] = acc[m][n][r2] + bi;
      }
    }
  }
}

extern "C" void kernel_launch(void* const* d_in, const int* in_sizes, int n_in,
                              void* d_out, int out_size, void* d_ws, size_t ws_size,
                              hipStream_t stream) {
  (void)in_sizes; (void)n_in; (void)out_size; (void)ws_size;
  const float* x    = (const float*)d_in[0];
  const float* Wqkv = (const float*)d_in[1];
  const float* bqkv = (const float*)d_in[2];
  const float* Wout = (const float*)d_in[3];
  const float* bout = (const float*)d_in[4];
  float* out = (float*)d_out;

  char* p = (char*)d_ws;
  u16* xb  = (u16*)p; p += (size_t)MT * EE * 2;           // 8 MB
  u16* wqT = (u16*)p; p += (size_t)NQ * EE * 2;           // 6 MB
  u16* woT = (u16*)p; p += (size_t)EE * EE * 2;           // 2 MB
  u16* Qs  = (u16*)p; p += (size_t)BB * HH * SS * DD * 2; // 8 MB
  u16* Ks  = (u16*)p; p += (size_t)BB * HH * SS * DD * 2; // 8 MB
  u16* Vt  = (u16*)p; p += (size_t)BB * HH * DD * SS * 2; // 8 MB
  u16* Ob  = (u16*)p; p += (size_t)MT * EE * 2;           // 8 MB

  cast_kernel<<<dim3((MT * EE / 4) / 256), dim3(256), 0, stream>>>(x, xb, MT * EE);
  transpose2_kernel<<<dim3(1024), dim3(256), 0, stream>>>(Wqkv, wqT, Wout, woT);
  gemm_qkv_kernel<<<dim3(768), dim3(256), 0, stream>>>(xb, wqT, bqkv, Qs, Ks, Vt);
  attn_kernel<<<dim3(256), dim3(1024), 0, stream>>>(Qs, Ks, Vt, Ob);
  gemm_out_kernel<<<dim3(256), dim3(256), 0, stream>>>(Ob, woT, bout, out);
}

// Round 26
// 115.032 us; speedup vs baseline: 2.1390x; 2.1390x over previous
//
#include <hip/hip_runtime.h>
#include <hip/hip_bf16.h>

#define BB 2
#define SS 2048
#define EE 1024
#define HH 16
#define DD 64
#define MT (BB*SS)     // 4096 tokens
#define NQ (3*EE)      // 3072

typedef unsigned short u16;
typedef __bf16 bf16t;
typedef bf16t bf16x8 __attribute__((ext_vector_type(8)));
typedef short short8v __attribute__((ext_vector_type(8)));
typedef float f32x4 __attribute__((ext_vector_type(4)));

#define AS1 __attribute__((address_space(1)))
#define AS3 __attribute__((address_space(3)))

__device__ __forceinline__ u16 f2b(float f) {
  unsigned u = __builtin_bit_cast(unsigned, f);
  u += 0x7FFF + ((u >> 16) & 1);   // RNE
  return (u16)(u >> 16);
}

__device__ __forceinline__ unsigned cvtpk(float lo, float hi) {
  unsigned r;
  asm("v_cvt_pk_bf16_f32 %0, %1, %2" : "=v"(r) : "v"(lo), "v"(hi));
  return r;
}

__device__ __forceinline__ void gload_lds16(const void* g, void* l) {
  __builtin_amdgcn_global_load_lds((const AS1 void*)(g), (AS3 void*)(l), 16, 0, 0);
}

__device__ __forceinline__ f32x4 mfma_bf16(short8v a, short8v b, f32x4 c) {
  return __builtin_amdgcn_mfma_f32_16x16x32_bf16(
      __builtin_bit_cast(bf16x8, a), __builtin_bit_cast(bf16x8, b), c, 0, 0, 0);
}

// scale folded into Q: 1/sqrt(64) * log2(e)
#define QSCALE 0.18033688f

// ---------------- prologue: cast x -> bf16 ----------------
__global__ void __launch_bounds__(256) cast_kernel(const float* __restrict__ in,
                                                   u16* __restrict__ out, int n) {
  int i = (blockIdx.x * 256 + threadIdx.x) * 4;
  if (i + 3 < n) {
    float4 v = *(const float4*)(in + i);
    ushort4 o;
    o.x = f2b(v.x); o.y = f2b(v.y); o.z = f2b(v.z); o.w = f2b(v.w);
    *(ushort4*)(out + i) = o;
  }
}

// Both W transposes in ONE launch. W [K][N] f32 -> WT [N][K] bf16, 64x64 tiles.
__global__ void __launch_bounds__(256) transpose2_kernel(
    const float* __restrict__ Wq, u16* __restrict__ WqT,
    const float* __restrict__ Wo, u16* __restrict__ WoT) {
  __shared__ float t[64][65];
  int bid = blockIdx.x;
  const float* W; u16* WT; int N, xt, yt;
  if (bid < 768) { W = Wq; WT = WqT; N = NQ; xt = bid % 48; yt = bid / 48; }
  else { int b2 = bid - 768; W = Wo; WT = WoT; N = EE; xt = b2 & 15; yt = b2 >> 4; }
  const int K = EE;
  int k0 = yt * 64, n0 = xt * 64;
  int r = threadIdx.x >> 4;          // 0..15
  int c4 = (threadIdx.x & 15) * 4;   // 0..60
#pragma unroll
  for (int i = 0; i < 4; ++i) {
    float4 v = *(const float4*)(W + (size_t)(k0 + r + i * 16) * N + n0 + c4);
    t[r + i * 16][c4 + 0] = v.x; t[r + i * 16][c4 + 1] = v.y;
    t[r + i * 16][c4 + 2] = v.z; t[r + i * 16][c4 + 3] = v.w;
  }
  __syncthreads();
#pragma unroll
  for (int i = 0; i < 4; ++i) {
    ushort4 o;
    o.x = f2b(t[c4 + 0][r + i * 16]); o.y = f2b(t[c4 + 1][r + i * 16]);
    o.z = f2b(t[c4 + 2][r + i * 16]); o.w = f2b(t[c4 + 3][r + i * 16]);
    *(ushort4*)(WT + (size_t)(n0 + r + i * 16) * K + k0 + c4) = o;
  }
}

// ---------------- QKV GEMM (2-phase dbuf + XCD swizzle) ---------------------
// 1D grid 768; each XCD owns 3 consecutive N-tiles (B-chunk 768KB stays
// L2-resident per XCD; A row-panels stream). T1 bijective: 768%8==0.
__global__ void __launch_bounds__(256) gemm_qkv_kernel(
    const u16* __restrict__ A, const u16* __restrict__ BT,
    const float* __restrict__ bias,
    u16* __restrict__ Qs, u16* __restrict__ Ks, u16* __restrict__ Vt) {
  __shared__ u16 As[8192];   // 2 x 128x32
  __shared__ u16 Bs[8192];
  const int K = EE;
  int tid = threadIdx.x;
  int w = tid >> 6, lane = tid & 63;
  int g = lane >> 4, q = lane & 15;
  int bid = blockIdx.x;
  int xcd = bid & 7, idx = bid >> 3;           // idx 0..95
  int xt = xcd * 3 + (idx % 3);                // 0..23
  int yt = idx / 3;                            // 0..31
  int m0 = yt * 128, n0 = xt * 128;
  int wm = (w >> 1) * 64, wn = (w & 1) * 64;

  f32x4 acc[4][4] = {};

  int r = tid >> 2;
  int kc = (tid & 3) * 8;
  const u16* ga = A + (size_t)(m0 + r) * K + kc;
  const u16* gb = BT + (size_t)(n0 + r) * K + kc;
  u16* lA0 = As + w * 512;
  u16* lA1 = As + 2048 + w * 512;
  u16* lB0 = Bs + w * 512;
  u16* lB1 = Bs + 2048 + w * 512;

  // prologue: stage k=0 into buf0
  gload_lds16(ga, lA0);
  gload_lds16(ga + 64 * K, lA1);
  gload_lds16(gb, lB0);
  gload_lds16(gb + 64 * K, lB1);
  ga += 32; gb += 32;
  __syncthreads();

  int cur = 0;
  for (int k0 = 0; k0 < K; k0 += 32) {
    if (k0 + 32 < K) {               // issue next-tile staging BEFORE compute
      int nx = (cur ^ 1) * 4096;
      gload_lds16(ga, lA0 + nx);
      gload_lds16(ga + 64 * K, lA1 + nx);
      gload_lds16(gb, lB0 + nx);
      gload_lds16(gb + 64 * K, lB1 + nx);
      ga += 32; gb += 32;
    }
    const u16* Ab = As + cur * 4096;
    const u16* Bb = Bs + cur * 4096;
    short8v af[4], bfv[4];
#pragma unroll
    for (int m = 0; m < 4; ++m)
      af[m] = *(const short8v*)(Ab + (wm + m * 16 + q) * 32 + g * 8);
#pragma unroll
    for (int n = 0; n < 4; ++n)
      bfv[n] = *(const short8v*)(Bb + (wn + n * 16 + q) * 32 + g * 8);
#pragma unroll
    for (int m = 0; m < 4; ++m)
#pragma unroll
      for (int n = 0; n < 4; ++n)
        acc[m][n] = mfma_bf16(af[m], bfv[n], acc[m][n]);
    __syncthreads();                 // drains staged loads; swap safe
    cur ^= 1;
  }

#pragma unroll
  for (int m = 0; m < 4; ++m) {
    int row0 = m0 + wm + m * 16 + g * 4;
#pragma unroll
    for (int n = 0; n < 4; ++n) {
      int col = n0 + wn + n * 16 + q;
      float bi = bias[col];
      int t = col >> 10;
      int h = (col >> 6) & 15;
      int d = col & 63;
      int b = row0 >> 11, s0 = row0 & 2047;
      size_t bh = (size_t)b * HH + h;
      if (t == 2) {
        ushort4 vv;
        vv.x = f2b(acc[m][n][0] + bi); vv.y = f2b(acc[m][n][1] + bi);
        vv.z = f2b(acc[m][n][2] + bi); vv.w = f2b(acc[m][n][3] + bi);
        *(ushort4*)&Vt[(bh * DD + d) * SS + s0] = vv;
      } else if (t == 0) {
#pragma unroll
        for (int r2 = 0; r2 < 4; ++r2)
          Qs[(bh * SS + s0 + r2) * DD + d] = f2b((acc[m][n][r2] + bi) * QSCALE);
      } else {
#pragma unroll
        for (int r2 = 0; r2 < 4; ++r2)
          Ks[(bh * SS + s0 + r2) * DD + d] = f2b(acc[m][n][r2] + bi);
      }
    }
  }
}

// ---------------- causal flash attention (round 19/21/24, best measured) ----
// 16 waves, halves hv=0/1 split the KV range of one 128-row chunk; triple-
// buffered K/V per half, counted vmcnt(2), rule-21 swizzle, swapped
// S^T=mfma(K,Q), LDS P roundtrip, defer-max, setprio around MFMA clusters.
__global__ void __launch_bounds__(1024) attn_kernel(
    const u16* __restrict__ Qg, const u16* __restrict__ Kg,
    const u16* __restrict__ Vg, u16* __restrict__ O) {
  // K: hv0 3x8K @0, hv1 3x8K @24576 | V: hv0 @49152, hv1 @73728
  // P: 16x2K @98304 (reused as merge partials 8x4K) | ml: 1K @131072
  __shared__ char lds[132096];
  const int tid = threadIdx.x;
  const int w = tid >> 6, lane = tid & 63;
  const int hv = w >> 3, ws = w & 7;
  const int g = lane >> 4, q = lane & 15;
  const int bid = blockIdx.x;          // 0..511
  const int bh = bid & 31;             // bid%8 -> XCD; K/V L2-resident
  const int p = 15 - (bid >> 5);       // LPT: longest chunks dispatch first
  const int b = bh >> 4, h = bh & 15;
  char* Pw = lds + 98304 + w * 2048;   // per-wave P buffer during loop
  const int qsw = (q & 7) << 4;        // swizzle for this lane's rows

  const char* Qp = (const char*)Qg + (size_t)bh * (SS * 128);
  const char* Kp = (const char*)Kg + (size_t)bh * (SS * 128);
  const char* Vp = (const char*)Vg + (size_t)bh * (SS * 128);  // [d][s]

  const int tl = tid & 511;
  const int srow = tl >> 3;
  const int ssw = ((tl & 7) * 16) ^ ((srow & 7) << 4);
  const char* Ksrc = Kp + srow * 128 + ssw;               // + s*8192
  const char* Vsrc = Vp + (size_t)srow * (SS * 2) + ssw;  // + s*128
  char* Kdst = lds + hv * 24576 + ws * 1024;              // + buf*8192
  char* Vdst = lds + 49152 + hv * 24576 + ws * 1024;

  const int hl = p + 1;                // tiles per half
  const int s0 = hv * hl, send = s0 + hl;
  const int qw = p * 128 + ws * 16;    // wave's first q row

  short8v aq0 = *(const short8v*)(Qp + (size_t)(qw + q) * 128 + g * 16);
  short8v aq1 = *(const short8v*)(Qp + (size_t)(qw + q) * 128 + 64 + g * 16);

  f32x4 oacc[4] = {};                  // O^T[d=vfi*16+g*4+r2][qrow=qw+q]
  float mrun = -1e30f, lrun = 0.f;

  gload_lds16(Ksrc + (size_t)s0 * 8192, Kdst);
  gload_lds16(Vsrc + s0 * 128, Vdst);
  if (hl > 1) {
    gload_lds16(Ksrc + (size_t)(s0 + 1) * 8192, Kdst + 8192);
    gload_lds16(Vsrc + (s0 + 1) * 128, Vdst + 8192);
  }

  for (int s = s0; s < send; ++s) {
    const int buf = (s - s0) % 3;
    if (s + 1 < send) asm volatile("s_waitcnt vmcnt(2)" ::: "memory");
    else              asm volatile("s_waitcnt vmcnt(0)" ::: "memory");
    __builtin_amdgcn_s_barrier();
    if (s + 2 < send) {
      int nb = (s + 2 - s0) % 3;
      gload_lds16(Ksrc + (size_t)(s + 2) * 8192, Kdst + nb * 8192);
      gload_lds16(Vsrc + (s + 2) * 128, Vdst + nb * 8192);
    }
    const int kv0 = s << 6;
    if (kv0 <= qw + 15) {
      const char* Kc = lds + hv * 24576 + buf * 8192;
      const char* Vc = lds + 49152 + hv * 24576 + buf * 8192;
      short8v kf[4][2];
#pragma unroll
      for (int cc = 0; cc < 4; ++cc) {
        const char* kb = Kc + (cc * 16 + q) * 128;
        kf[cc][0] = *(const short8v*)(kb + ((g * 16) ^ qsw));
        kf[cc][1] = *(const short8v*)(kb + ((64 + g * 16) ^ qsw));
      }
      f32x4 st[4];
      __builtin_amdgcn_s_setprio(1);
#pragma unroll
      for (int cc = 0; cc < 4; ++cc) {
        f32x4 z = {};
        z = mfma_bf16(kf[cc][0], aq0, z);
        z = mfma_bf16(kf[cc][1], aq1, z);
        st[cc] = z;
      }
      __builtin_amdgcn_s_setprio(0);
      short8v vf[4][2];
#pragma unroll
      for (int v = 0; v < 4; ++v) {
        const char* vb = Vc + (v * 16 + q) * 128;
        vf[v][0] = *(const short8v*)(vb + ((g * 16) ^ qsw));
        vf[v][1] = *(const short8v*)(vb + ((64 + g * 16) ^ qsw));
      }
      if (kv0 + 63 > qw) {
        int row = qw + q;
#pragma unroll
        for (int cc = 0; cc < 4; ++cc) {
          int kvb = kv0 + cc * 16 + g * 4;
#pragma unroll
          for (int r2 = 0; r2 < 4; ++r2)
            if (kvb + r2 > row) st[cc][r2] = -1e30f;
        }
      }
      f32x4 t01, t23;
#pragma unroll
      for (int r2 = 0; r2 < 4; ++r2) {
        t01[r2] = fmaxf(st[0][r2], st[1][r2]);
        t23[r2] = fmaxf(st[2][r2], st[3][r2]);
      }
      float mx = fmaxf(fmaxf(fmaxf(t01[0], t01[1]), fmaxf(t01[2], t01[3])),
                       fmaxf(fmaxf(t23[0], t23[1]), fmaxf(t23[2], t23[3])));
      mx = fmaxf(mx, __shfl_xor(mx, 16));
      mx = fmaxf(mx, __shfl_xor(mx, 32));
      if (!__all(mx - mrun <= 8.f)) {  // T13: rescale only on real growth
        float mnew = fmaxf(mrun, mx);
        float alpha = exp2f(mrun - mnew);
        mrun = mnew;
        lrun *= alpha;
#pragma unroll
        for (int vfi = 0; vfi < 4; ++vfi)
#pragma unroll
          for (int r2 = 0; r2 < 4; ++r2) oacc[vfi][r2] *= alpha;
      }
      f32x4 sum4 = {};
#pragma unroll
      for (int cc = 0; cc < 4; ++cc)
#pragma unroll
        for (int r2 = 0; r2 < 4; ++r2) {
          float pv = exp2f(st[cc][r2] - mrun);
          st[cc][r2] = pv;
          sum4[r2] += pv;
        }
      float sm = (sum4[0] + sum4[1]) + (sum4[2] + sum4[3]);
      sm += __shfl_xor(sm, 16);
      sm += __shfl_xor(sm, 32);
      lrun += sm;
      char* basep = Pw + q * 128;
#pragma unroll
      for (int cc = 0; cc < 4; ++cc) {
        unsigned p01 = cvtpk(st[cc][0], st[cc][1]);
        unsigned p23 = cvtpk(st[cc][2], st[cc][3]);
        *(unsigned*)(basep + ((32 * cc + 8 * g + 0) ^ qsw)) = p01;
        *(unsigned*)(basep + ((32 * cc + 8 * g + 4) ^ qsw)) = p23;
      }
      short8v pa0 = *(const short8v*)(basep + ((g * 16) ^ qsw));
      short8v pa1 = *(const short8v*)(basep + ((64 + g * 16) ^ qsw));
      __builtin_amdgcn_s_setprio(1);
#pragma unroll
      for (int vfi = 0; vfi < 4; ++vfi) {
        oacc[vfi] = mfma_bf16(vf[vfi][0], pa0, oacc[vfi]);
        oacc[vfi] = mfma_bf16(vf[vfi][1], pa1, oacc[vfi]);
      }
      __builtin_amdgcn_s_setprio(0);
    }
  }

  __syncthreads();
  if (hv) {
    char* ob = lds + 98304 + ws * 4096;
#pragma unroll
    for (int vfi = 0; vfi < 4; ++vfi)
      *(f32x4*)(ob + vfi * 1024 + lane * 16) = oacc[vfi];
    if (g == 0)
      *(float2*)(lds + 131072 + (ws * 16 + q) * 8) = make_float2(mrun, lrun);
  }
  __syncthreads();
  if (!hv) {
    float2 ml = *(const float2*)(lds + 131072 + (ws * 16 + q) * 8);
    float mf = fmaxf(mrun, ml.x);
    float a0 = exp2f(mrun - mf);
    float a1 = exp2f(ml.x - mf);
    float inv = 1.0f / (a0 * lrun + a1 * ml.y);
    a0 *= inv; a1 *= inv;
    const char* ob = lds + 98304 + ws * 4096;
    int row = qw + q;
    char* obase = (char*)O + (((size_t)b * SS + row) * EE + h * 64) * 2;
#pragma unroll
    for (int vfi = 0; vfi < 4; ++vfi) {
      f32x4 o1 = *(const f32x4*)(ob + vfi * 1024 + lane * 16);
      uint2 o;
      o.x = cvtpk(a0 * oacc[vfi][0] + a1 * o1[0],
                  a0 * oacc[vfi][1] + a1 * o1[1]);
      o.y = cvtpk(a0 * oacc[vfi][2] + a1 * o1[2],
                  a0 * oacc[vfi][3] + a1 * o1[3]);
      *(uint2*)(obase + (vfi * 16 + g * 4) * 2) = o;
    }
  }
}

// ---------------- output projection GEMM (2-phase dbuf + XCD swizzle) -------
// 1D grid 256; each XCD owns one N-tile column (B-chunk 256KB L2-resident).
__global__ void __launch_bounds__(256) gemm_out_kernel(
    const u16* __restrict__ A, const u16* __restrict__ BT,
    const float* __restrict__ bias, float* __restrict__ Cout) {
  __shared__ u16 As[8192];
  __shared__ u16 Bs[8192];
  const int K = EE;
  int tid = threadIdx.x;
  int w = tid >> 6, lane = tid & 63;
  int g = lane >> 4, q = lane & 15;
  int bid = blockIdx.x;
  int xt = bid & 7, yt = bid >> 3;     // xcd-owned N column
  int m0 = yt * 128, n0 = xt * 128;
  int wm = (w >> 1) * 64, wn = (w & 1) * 64;

  f32x4 acc[4][4] = {};

  int r = tid >> 2;
  int kc = (tid & 3) * 8;
  const u16* ga = A + (size_t)(m0 + r) * K + kc;
  const u16* gb = BT + (size_t)(n0 + r) * K + kc;
  u16* lA0 = As + w * 512;
  u16* lA1 = As + 2048 + w * 512;
  u16* lB0 = Bs + w * 512;
  u16* lB1 = Bs + 2048 + w * 512;

  gload_lds16(ga, lA0);
  gload_lds16(ga + 64 * K, lA1);
  gload_lds16(gb, lB0);
  gload_lds16(gb + 64 * K, lB1);
  ga += 32; gb += 32;
  __syncthreads();

  int cur = 0;
  for (int k0 = 0; k0 < K; k0 += 32) {
    if (k0 + 32 < K) {
      int nx = (cur ^ 1) * 4096;
      gload_lds16(ga, lA0 + nx);
      gload_lds16(ga + 64 * K, lA1 + nx);
      gload_lds16(gb, lB0 + nx);
      gload_lds16(gb + 64 * K, lB1 + nx);
      ga += 32; gb += 32;
    }
    const u16* Ab = As + cur * 4096;
    const u16* Bb = Bs + cur * 4096;
    short8v af[4], bfv[4];
#pragma unroll
    for (int m = 0; m < 4; ++m)
      af[m] = *(const short8v*)(Ab + (wm + m * 16 + q) * 32 + g * 8);
#pragma unroll
    for (int n = 0; n < 4; ++n)
      bfv[n] = *(const short8v*)(Bb + (wn + n * 16 + q) * 32 + g * 8);
#pragma unroll
    for (int m = 0; m < 4; ++m)
#pragma unroll
      for (int n = 0; n < 4; ++n)
        acc[m][n] = mfma_bf16(af[m], bfv[n], acc[m][n]);
    __syncthreads();
    cur ^= 1;
  }

#pragma unroll
  for (int m = 0; m < 4; ++m) {
    int row0 = m0 + wm + m * 16 + g * 4;
#pragma unroll
    for (int n = 0; n < 4; ++n) {
      int col = n0 + wn + n * 16 + q;
      float bi = bias[col];
#pragma unroll
      for (int r2 = 0; r2 < 4; ++r2) {
        int row = row0 + r2;
        Cout[(size_t)row * EE + col] = acc[m][n][r2] + bi;
      }
    }
  }
}

extern "C" void kernel_launch(void* const* d_in, const int* in_sizes, int n_in,
                              void* d_out, int out_size, void* d_ws, size_t ws_size,
                              hipStream_t stream) {
  (void)in_sizes; (void)n_in; (void)out_size; (void)ws_size;
  const float* x    = (const float*)d_in[0];
  const float* Wqkv = (const float*)d_in[1];
  const float* bqkv = (const float*)d_in[2];
  const float* Wout = (const float*)d_in[3];
  const float* bout = (const float*)d_in[4];
  float* out = (float*)d_out;

  char* p = (char*)d_ws;
  u16* xb  = (u16*)p; p += (size_t)MT * EE * 2;           // 8 MB
  u16* wqT = (u16*)p; p += (size_t)NQ * EE * 2;           // 6 MB
  u16* woT = (u16*)p; p += (size_t)EE * EE * 2;           // 2 MB
  u16* Qs  = (u16*)p; p += (size_t)BB * HH * SS * DD * 2; // 8 MB
  u16* Ks  = (u16*)p; p += (size_t)BB * HH * SS * DD * 2; // 8 MB
  u16* Vt  = (u16*)p; p += (size_t)BB * HH * DD * SS * 2; // 8 MB
  u16* Ob  = (u16*)p; p += (size_t)MT * EE * 2;           // 8 MB

  cast_kernel<<<dim3((MT * EE / 4) / 256), dim3(256), 0, stream>>>(x, xb, MT * EE);
  transpose2_kernel<<<dim3(1024), dim3(256), 0, stream>>>(Wqkv, wqT, Wout, woT);
  gemm_qkv_kernel<<<dim3(768), dim3(256), 0, stream>>>(xb, wqT, bqkv, Qs, Ks, Vt);
  attn_kernel<<<dim3(512), dim3(1024), 0, stream>>>(Qs, Ks, Vt, Ob);
  gemm_out_kernel<<<dim3(256), dim3(256), 0, stream>>>(Ob, woT, bout, out);
}